// Round 1
// baseline (372.146 us; speedup 1.0000x reference)
//
#include <hip/hip_runtime.h>

#define N_USERS 100000
#define N_ITEMS 50001
#define N_EDGES 1000000
#define D 64
#define BATCH 4096
#define MAXLEN 50

// coarse buckets, fixed capacity (no hist/scan): counts ~N(2560,51), CAP=3072 is 10 sigma
#define SHU 8
#define SHI 7
#define NBU ((N_USERS + 255) >> 8)    // 391
#define NBI ((N_ITEMS + 127) >> 7)    // 391
#define CAP 3072
#define BEPB 8192
#define BBLOCKS ((N_EDGES + BEPB - 1) / BEPB) // 123

// source chunking for per-XCD L2 residency (4 MB/XCD):
// users-gather source = item rows (6.4 MB bf16) -> 2 chunks of ~3.2 MB
// items-gather source = user rows (12.8 MB bf16) -> 4 chunks of ~3.2 MB
#define NCH_U 2
#define NCH_I 4
#define UCHUNK_SPLIT 25024
#define ICHUNK_DIV 25000u

typedef __attribute__((ext_vector_type(8))) short short8;
typedef __attribute__((ext_vector_type(4))) float f32x4;

// ---------- bf16 helpers ----------
__device__ __forceinline__ float bf_lo(unsigned u) { return __uint_as_float(u << 16); }
__device__ __forceinline__ float bf_hi(unsigned u) { return __uint_as_float(u & 0xffff0000u); }
__device__ __forceinline__ float bf_s(unsigned short s) { return __uint_as_float(((unsigned)s) << 16); }
__device__ __forceinline__ unsigned bf_pack2(float a, float b) {
    unsigned ba = __float_as_uint(a);
    unsigned bb = __float_as_uint(b);
    ba += 0x7fffu + ((ba >> 16) & 1u);
    bb += 0x7fffu + ((bb >> 16) & 1u);
    return (ba >> 16) | (bb & 0xffff0000u);
}
__device__ __forceinline__ float fast_tanh(float x) {
    float e = __expf(2.0f * x);
    return 1.0f - 2.0f * __builtin_amdgcn_rcpf(e + 1.0f);
}

// ---------------- fp32 -> bf16 table convert ----------------
__global__ __launch_bounds__(256) void convert_kernel(
    const float* __restrict__ src, unsigned* __restrict__ dst, int npairs)
{
    int i = blockIdx.x * 256 + threadIdx.x;
    if (i < npairs) {
        float2 f = ((const float2*)src)[i];
        dst[i] = bf_pack2(f.x, f.y);
    }
}

// ---------------- pass A: bin edges into fixed-capacity buckets ----------------
// staged entry (8 B): .x = (row_local << 16) | q_val, .y = src_idx
__global__ __launch_bounds__(512) void bin_kernel(
    const int* __restrict__ eu, const int* __restrict__ ei,
    const float* __restrict__ ev_uv, const float* __restrict__ ev_vu,
    int* __restrict__ gcur_u, int* __restrict__ gcur_i,
    int2* __restrict__ staged_u, int2* __restrict__ staged_i)
{
    __shared__ int hist[NBU];
    __shared__ int runbase[NBU];
    __shared__ unsigned short rank[BEPB];
    int tid = threadIdx.x;
    int dir_i = (blockIdx.x >= BBLOCKS) ? 1 : 0;
    int blk = blockIdx.x - (dir_i ? BBLOCKS : 0);
    const int* erow = dir_i ? ei : eu;
    const int* esrc = dir_i ? eu : ei;
    const float* eval = dir_i ? ev_vu : ev_uv;
    int* gcur = dir_i ? gcur_i : gcur_u;
    int2* staged = dir_i ? staged_i : staged_u;
    const int shift = dir_i ? SHI : SHU;
    const float qs = dir_i ? 32767.0f : 65535.0f;
    const int rlmask = dir_i ? 127 : 255;
    const int nb = dir_i ? NBI : NBU;

    for (int i = tid; i < nb; i += 512) hist[i] = 0;
    __syncthreads();
    int e0 = blk * BEPB;
    for (int k = 0; k < BEPB / 512; ++k) {
        int slot = k * 512 + tid;
        int e = e0 + slot;
        if (e < N_EDGES)
            rank[slot] = (unsigned short)atomicAdd(&hist[erow[e] >> shift], 1);
    }
    __syncthreads();
    for (int i = tid; i < nb; i += 512) {
        int cn = hist[i];
        runbase[i] = cn ? (i * CAP + atomicAdd(&gcur[i], cn)) : 0;
    }
    __syncthreads();
    for (int k = 0; k < BEPB / 512; ++k) {
        int slot = k * 512 + tid;
        int e = e0 + slot;
        if (e < N_EDGES) {
            int row = erow[e];
            unsigned q = (unsigned)(fminf(fmaxf(eval[e], 0.0f), 1.0f) * qs + 0.5f);
            int2 en;
            en.x = (int)((unsigned)(row & rlmask) << 16 | q);
            en.y = esrc[e];
            staged[runbase[row >> shift] + rank[slot]] = en;
        }
    }
}

// ---------------- pass B: place within bucket, sorted by (row, src-chunk) ----------------
// counters: rl*NCH + c  (256*2 = 128*4 = 512 for both directions)
__global__ __launch_bounds__(512) void place_kernel(
    const int2* __restrict__ staged_u, const int2* __restrict__ staged_i,
    const int* __restrict__ gcur_u, const int* __restrict__ gcur_i,
    unsigned* __restrict__ csr_u, unsigned* __restrict__ csr_i,
    int2* __restrict__ offend_u, int2* __restrict__ offend_i)
{
    __shared__ int cnt[512];
    __shared__ int s[512];
    __shared__ int cur[512];
    int tid = threadIdx.x;
    int dir_i = (blockIdx.x >= NBU) ? 1 : 0;
    int b = blockIdx.x - (dir_i ? NBU : 0);
    const int2* staged = dir_i ? staged_i : staged_u;
    const int* gcur = dir_i ? gcur_i : gcur_u;
    unsigned* csr = dir_i ? csr_i : csr_u;
    int2* offend = dir_i ? offend_i : offend_u;
    const int NR = dir_i ? 128 : 256;
    const int NCH = dir_i ? NCH_I : NCH_U;
    const int nrows = dir_i ? N_ITEMS : N_USERS;
    const int idxbits = dir_i ? 17 : 16;

    int sb = b * CAP;
    int eb = sb + gcur[b];
    cnt[tid] = 0;
    __syncthreads();
    for (int idx = sb + tid; idx < eb; idx += 512) {
        int2 en = staged[idx];
        int rl = ((unsigned)en.x) >> 16;
        int c = dir_i ? (int)((unsigned)en.y / ICHUNK_DIV)
                      : (en.y >= UCHUNK_SPLIT ? 1 : 0);
        atomicAdd(&cnt[rl * NCH + c], 1);
    }
    __syncthreads();
    int cv = cnt[tid];
    s[tid] = cv;
    __syncthreads();
    for (int off = 1; off < 512; off <<= 1) {
        int v = (tid >= off) ? s[tid - off] : 0;
        __syncthreads();
        s[tid] += v;
        __syncthreads();
    }
    int excl = s[tid] - cv;
    {
        int rl = tid / NCH;
        int c = tid - rl * NCH;
        int row = b * NR + rl;
        if (row < nrows) {
            int2 oe;
            oe.x = sb + excl;
            oe.y = sb + excl + cv;
            offend[(size_t)row * NCH + c] = oe;
        }
    }
    cur[tid] = sb + excl;
    __syncthreads();
    for (int idx = sb + tid; idx < eb; idx += 512) {
        int2 en = staged[idx];
        unsigned w0 = (unsigned)en.x;
        int rl = w0 >> 16;
        unsigned q = w0 & 0xFFFFu;
        int c = dir_i ? (int)((unsigned)en.y / ICHUNK_DIV)
                      : (en.y >= UCHUNK_SPLIT ? 1 : 0);
        int pos = atomicAdd(&cur[rl * NCH + c], 1);
        csr[pos] = (q << idxbits) | (unsigned)en.y;
    }
}

// ---------------- gather spmm: quarter-wave per ROW ----------------
template<int IDXBITS>
__device__ __forceinline__ void gather_row_q16(
    const unsigned* __restrict__ src, const unsigned* __restrict__ csr,
    int o, int e, int c8, int qq,
    float& A0, float& A1, float& A2, float& A3)
{
    constexpr unsigned MASK = (1u << IDXBITS) - 1u;
    constexpr float SCALE = 1.0f / (float)((1u << (32 - IDXBITS)) - 1u);
    float a0 = 0.f, a1 = 0.f, a2 = 0.f, a3 = 0.f;
    for (int base = o; base < e; base += 16) {
        int n = min(16, e - base);
        unsigned word = 0;
        if (c8 < n) word = __builtin_nontemporal_load(csr + base + c8);
#pragma unroll 4
        for (int j = 0; j < n; ++j) {
            unsigned wj = (unsigned)__shfl((int)word, 16 * qq + j, 64);
            int r = (int)(wj & MASK);
            float v = (float)(wj >> IDXBITS) * SCALE;
            uint2 u2 = *(const uint2*)(src + (size_t)r * 32 + 2 * c8);
            a0 = fmaf(v, bf_lo(u2.x), a0);
            a1 = fmaf(v, bf_hi(u2.x), a1);
            a2 = fmaf(v, bf_lo(u2.y), a2);
            a3 = fmaf(v, bf_hi(u2.y), a3);
        }
    }
    A0 = a0; A1 = a1; A2 = a2; A3 = a3;
}

// one source-chunk pass.
// MODE 0: part[row] = a          (nt f32 store; initializes every row)
// MODE 1: part[row] += a         (nt f32 rmw)
// MODE 2: dst_bf16[row] = part[row] + a  (finalize)
template<int IDXBITS, int NCH, int MODE>
__global__ __launch_bounds__(256) void gather_pass_kernel(
    const unsigned* __restrict__ src, const unsigned* __restrict__ csr,
    const int2* __restrict__ offend, int chunk,
    float* __restrict__ part, unsigned* __restrict__ dst, int nrows)
{
    int gw = (blockIdx.x * 256 + threadIdx.x) >> 6;
    int lane = threadIdx.x & 63;
    int qq = lane >> 4, c8 = lane & 15;
    int row = gw * 4 + qq;
    int2 oe = (row < nrows) ? offend[(size_t)row * NCH + chunk] : make_int2(0, 0);
    float a0, a1, a2, a3;
    gather_row_q16<IDXBITS>(src, csr, oe.x, oe.y, c8, qq, a0, a1, a2, a3);
    if (row < nrows) {
        f32x4* pp = (f32x4*)(part + (size_t)row * 64) + c8;
        if constexpr (MODE == 0) {
            f32x4 v;
            v[0] = a0; v[1] = a1; v[2] = a2; v[3] = a3;
            __builtin_nontemporal_store(v, pp);
        } else if constexpr (MODE == 1) {
            f32x4 p = __builtin_nontemporal_load(pp);
            p[0] += a0; p[1] += a1; p[2] += a2; p[3] += a3;
            __builtin_nontemporal_store(p, pp);
        } else {
            f32x4 p = __builtin_nontemporal_load(pp);
            uint2 o2;
            o2.x = bf_pack2(p[0] + a0, p[1] + a1);
            o2.y = bf_pack2(p[2] + a2, p[3] + a3);
            *((uint2*)(dst + (size_t)row * 32) + c8) = o2;
        }
    }
}

// final items chunk (NCH_I-1) fused with Vf = (V0 + V1 + V2)/3 + V0; Vf packed bf16
__global__ __launch_bounds__(256) void gather_final2_kernel(
    const unsigned* __restrict__ src, const unsigned* __restrict__ csr,
    const int2* __restrict__ offend,
    const float* __restrict__ part,
    const float* __restrict__ V0, const unsigned* __restrict__ V1bf,
    unsigned* __restrict__ Vf_bf)
{
    int gw = (blockIdx.x * 256 + threadIdx.x) >> 6;
    int lane = threadIdx.x & 63;
    int qq = lane >> 4, c8 = lane & 15;
    int row = gw * 4 + qq;
    int2 oe = (row < N_ITEMS) ? offend[(size_t)row * NCH_I + (NCH_I - 1)] : make_int2(0, 0);
    float a0, a1, a2, a3;
    gather_row_q16<17>(src, csr, oe.x, oe.y, c8, qq, a0, a1, a2, a3);
    if (row < N_ITEMS) {
        f32x4 p = __builtin_nontemporal_load((const f32x4*)(part + (size_t)row * 64) + c8);
        float4 v0 = *((const float4*)(V0 + (size_t)row * 64) + c8);
        uint2 u1 = *((const uint2*)(V1bf + (size_t)row * 32) + c8);
        float s0 = p[0] + a0, s1 = p[1] + a1, s2 = p[2] + a2, s3 = p[3] + a3;
        float r0 = (v0.x + bf_lo(u1.x) + s0) * (1.0f / 3.0f) + v0.x;
        float r1 = (v0.y + bf_hi(u1.x) + s1) * (1.0f / 3.0f) + v0.y;
        float r2 = (v0.z + bf_lo(u1.y) + s2) * (1.0f / 3.0f) + v0.z;
        float r3 = (v0.w + bf_hi(u1.y) + s3) * (1.0f / 3.0f) + v0.w;
        uint2 o2;
        o2.x = bf_pack2(r0, r1);
        o2.y = bf_pack2(r2, r3);
        *((uint2*)(Vf_bf + (size_t)row * 32) + c8) = o2;
    }
}

// ---------------- attention pooling via MFMA (round-8, verified) ----------------
__global__ __launch_bounds__(256) void phase2_kernel(
    const float* __restrict__ user_table, const unsigned* __restrict__ Vf_bf,
    const float* __restrict__ Watt, const float* __restrict__ Wb,
    const float* __restrict__ Wagg, const int* __restrict__ uidx,
    const int* __restrict__ ctx, float* __restrict__ out)
{
    __shared__ __align__(16) unsigned seq[4][64 * 36];
    __shared__ unsigned short wgT[64 * 72];
    __shared__ __align__(16) float idrow[4][64];
    __shared__ float attn_l[4][64];
    __shared__ float pooled_l[4][64];

    const int tid = threadIdx.x;
    const int w = tid >> 6;
    const int lane = tid & 63;
    const int q = lane >> 4;
    const int n = lane & 15;
    const int b = blockIdx.x * 4 + w;

    for (int i = tid; i < 64 * 64; i += 256) {
        int e = i >> 6, d = i & 63;
        unsigned bb = __float_as_uint(Wagg[i]);
        bb += 0x7fffu + ((bb >> 16) & 1u);
        wgT[d * 72 + e] = (unsigned short)(bb >> 16);
    }
    __syncthreads();

    short8 wa_f[4][2];
#pragma unroll
    for (int et = 0; et < 4; ++et)
#pragma unroll
        for (int ks = 0; ks < 2; ++ks) {
            const float* rp = Watt + (size_t)(16 * et + n) * 64 + 32 * ks + 8 * q;
            float4 f0 = *(const float4*)rp;
            float4 f1 = *(const float4*)(rp + 4);
            union { short8 s; unsigned u[4]; } t;
            t.u[0] = bf_pack2(f0.x, f0.y);
            t.u[1] = bf_pack2(f0.z, f0.w);
            t.u[2] = bf_pack2(f1.x, f1.y);
            t.u[3] = bf_pack2(f1.z, f1.w);
            wa_f[et][ks] = t.s;
        }
    f32x4 biasv[4];
#pragma unroll
    for (int et = 0; et < 4; ++et)
        biasv[et] = *(const f32x4*)(Wb + 16 * et + 4 * q);
    short8 ones8;
#pragma unroll
    for (int j = 0; j < 8; ++j) ones8[j] = (short)0x3F80;

    int uid = uidx[b];
    idrow[w][lane] = user_table[(size_t)uid * 64 + lane];
    f32x4 idv[4];
#pragma unroll
    for (int et = 0; et < 4; ++et)
        idv[et] = *(f32x4*)&idrow[w][16 * et + 4 * q];

    int ci = (lane < MAXLEN) ? ctx[b * MAXLEN + lane] : 0;
#pragma unroll 5
    for (int it = 0; it < 25; ++it) {
        int l = 2 * it + (lane >> 5);
        int cc = lane & 31;
        int rsrc = __shfl(ci, l, 64);
        seq[w][l * 36 + cc] = Vf_bf[(size_t)rsrc * 32 + cc];
    }

    float xs[4];
#pragma unroll
    for (int lt = 0; lt < 4; ++lt) {
        union { short8 s; uint4 u; } B0, B1;
        B0.u = *(const uint4*)&seq[w][(16 * lt + n) * 36 + 4 * q];
        B1.u = *(const uint4*)&seq[w][(16 * lt + n) * 36 + 16 + 4 * q];

        f32x4 rsum = {0.f, 0.f, 0.f, 0.f};
        rsum = __builtin_amdgcn_mfma_f32_16x16x32_bf16(ones8, B0.s, rsum, 0, 0, 0);
        rsum = __builtin_amdgcn_mfma_f32_16x16x32_bf16(ones8, B1.s, rsum, 0, 0, 0);
        float rsv = rsum[0];

        float xacc = 0.0f;
#pragma unroll
        for (int et = 0; et < 4; ++et) {
            f32x4 a = {0.f, 0.f, 0.f, 0.f};
            a = __builtin_amdgcn_mfma_f32_16x16x32_bf16(wa_f[et][0], B0.s, a, 0, 0, 0);
            a = __builtin_amdgcn_mfma_f32_16x16x32_bf16(wa_f[et][1], B1.s, a, 0, 0, 0);
#pragma unroll
            for (int r = 0; r < 4; ++r) {
                float t = fast_tanh(a[r] + biasv[et][r]);
                xacc = fmaf(t, idv[et][r], xacc);
            }
        }
        xacc += __shfl_xor(xacc, 16, 64);
        xacc += __shfl_xor(xacc, 32, 64);
        xs[lt] = (rsv == 0.0f) ? 0.0f : xacc;
    }

    float ex[4];
    float tot = 0.0f;
#pragma unroll
    for (int lt = 0; lt < 4; ++lt) {
        int l = 16 * lt + n;
        ex[lt] = (l < MAXLEN) ? __expf(xs[lt]) : 0.0f;
        tot += ex[lt];
    }
    tot += __shfl_xor(tot, 1, 64);
    tot += __shfl_xor(tot, 2, 64);
    tot += __shfl_xor(tot, 4, 64);
    tot += __shfl_xor(tot, 8, 64);
    float inv = 1.0f / (tot + 1e-12f);
    if (lane < 16) {
#pragma unroll
        for (int lt = 0; lt < 4; ++lt)
            attn_l[w][16 * lt + lane] = ex[lt] * inv;
    }

    float pooled = 0.0f;
    for (int l = 0; l < MAXLEN; ++l) {
        float a = attn_l[w][l];
        unsigned uu = seq[w][l * 36 + (lane >> 1)];
        float sv = (lane & 1) ? bf_hi(uu) : bf_lo(uu);
        pooled = fmaf(a, sv, pooled);
    }
    pooled_l[w][lane] = pooled;

    float o = 0.0f;
#pragma unroll 8
    for (int d = 0; d < 64; ++d) {
        float pv = pooled_l[w][d];
        float wv = bf_s(wgT[d * 72 + lane]);
        o = fmaf(pv, wv, o);
    }
    out[(size_t)b * 64 + lane] = 0.5f * idrow[w][lane] + 0.5f * o;
}

// ---------------- launch ----------------

extern "C" void kernel_launch(void* const* d_in, const int* in_sizes, int n_in,
                              void* d_out, int out_size, void* d_ws, size_t ws_size,
                              hipStream_t stream)
{
    const float* user_table = (const float*)d_in[0];
    const float* item_table = (const float*)d_in[1];
    const float* ev_uv      = (const float*)d_in[2];
    const float* ev_vu      = (const float*)d_in[3];
    const float* Watt       = (const float*)d_in[4];
    const float* Wb         = (const float*)d_in[5];
    const float* Wagg       = (const float*)d_in[6];
    const int*   edge_u     = (const int*)d_in[7];
    const int*   edge_i     = (const int*)d_in[8];
    const int*   uidx       = (const int*)d_in[9];
    const int*   ctx        = (const int*)d_in[10];
    float* out = (float*)d_out;

    const size_t NCAP = (size_t)NBU * CAP;  // 1201152 entries per direction

    // workspace layout (~96 MB)
    char* p = (char*)d_ws;
    unsigned* it_bf    = (unsigned*)p; p += (size_t)N_ITEMS * 32 * 4;   // 6.4 MB
    unsigned* u_msg_bf = (unsigned*)p; p += (size_t)N_USERS * 32 * 4;   // 12.8 MB
    unsigned* V1_bf    = (unsigned*)p; p += (size_t)N_ITEMS * 32 * 4;   // 6.4 MB
    // staged region (19.2 MB) — Vf_bf (6.4 MB) aliases it; staged dead by then
    char*     Sreg     = p;            p += NCAP * 8 * 2;               // 19.2 MB
    int2*     staged_u = (int2*)Sreg;
    int2*     staged_i = (int2*)(Sreg + NCAP * 8);
    unsigned* Vf_bf    = (unsigned*)Sreg;
    unsigned* csr_u    = (unsigned*)p; p += NCAP * 4;                   // 4.8 MB
    unsigned* csr_i    = (unsigned*)p; p += NCAP * 4;                   // 4.8 MB
    int2*     offend_u = (int2*)p;     p += (size_t)N_USERS * NCH_U * 8; // 1.6 MB
    int2*     offend_i = (int2*)p;     p += (size_t)N_ITEMS * NCH_I * 8; // 1.6 MB
    float*    u_part   = (float*)p;    p += (size_t)N_USERS * 64 * 4;   // 25.6 MB
    float*    i_part   = (float*)p;    p += (size_t)N_ITEMS * 64 * 4;   // 12.8 MB
    int*      gcur_u   = (int*)p;      p += NBU * 4;                    // contiguous
    int*      gcur_i   = (int*)p;      p += NBI * 4;                    //  pair

    // zero within-bucket cursors
    hipMemsetAsync(gcur_u, 0, (NBU + NBI) * 4, stream);

    convert_kernel<<<(N_ITEMS * 32 + 255) / 256, 256, 0, stream>>>(
        item_table, it_bf, N_ITEMS * 32);

    bin_kernel<<<2 * BBLOCKS, 512, 0, stream>>>(edge_u, edge_i, ev_uv, ev_vu,
                                                gcur_u, gcur_i, staged_u, staged_i);
    place_kernel<<<NBU + NBI, 512, 0, stream>>>(staged_u, staged_i, gcur_u, gcur_i,
                                                csr_u, csr_i, offend_u, offend_i);

    // 16 rows per block (4 waves x 4 quarter-rows)
    const int ublocks = (N_USERS + 15) / 16;
    const int iblocks = (N_ITEMS + 15) / 16;

    // layer 1: u_msg = UV @ V0  (2 source chunks)
    gather_pass_kernel<16, NCH_U, 0><<<ublocks, 256, 0, stream>>>(
        it_bf, csr_u, offend_u, 0, u_part, nullptr, N_USERS);
    gather_pass_kernel<16, NCH_U, 2><<<ublocks, 256, 0, stream>>>(
        it_bf, csr_u, offend_u, 1, u_part, u_msg_bf, N_USERS);
    // layer 1: V1 = VU @ u_msg  (4 source chunks)
    gather_pass_kernel<17, NCH_I, 0><<<iblocks, 256, 0, stream>>>(
        u_msg_bf, csr_i, offend_i, 0, i_part, nullptr, N_ITEMS);
    gather_pass_kernel<17, NCH_I, 1><<<iblocks, 256, 0, stream>>>(
        u_msg_bf, csr_i, offend_i, 1, i_part, nullptr, N_ITEMS);
    gather_pass_kernel<17, NCH_I, 1><<<iblocks, 256, 0, stream>>>(
        u_msg_bf, csr_i, offend_i, 2, i_part, nullptr, N_ITEMS);
    gather_pass_kernel<17, NCH_I, 2><<<iblocks, 256, 0, stream>>>(
        u_msg_bf, csr_i, offend_i, 3, i_part, V1_bf, N_ITEMS);

    // layer 2: u_msg2 = UV @ V1
    gather_pass_kernel<16, NCH_U, 0><<<ublocks, 256, 0, stream>>>(
        V1_bf, csr_u, offend_u, 0, u_part, nullptr, N_USERS);
    gather_pass_kernel<16, NCH_U, 2><<<ublocks, 256, 0, stream>>>(
        V1_bf, csr_u, offend_u, 1, u_part, u_msg_bf, N_USERS);
    // layer 2: V2 = VU @ u_msg2 (+ fused combine -> Vf bf16 on last chunk)
    gather_pass_kernel<17, NCH_I, 0><<<iblocks, 256, 0, stream>>>(
        u_msg_bf, csr_i, offend_i, 0, i_part, nullptr, N_ITEMS);
    gather_pass_kernel<17, NCH_I, 1><<<iblocks, 256, 0, stream>>>(
        u_msg_bf, csr_i, offend_i, 1, i_part, nullptr, N_ITEMS);
    gather_pass_kernel<17, NCH_I, 1><<<iblocks, 256, 0, stream>>>(
        u_msg_bf, csr_i, offend_i, 2, i_part, nullptr, N_ITEMS);
    gather_final2_kernel<<<iblocks, 256, 0, stream>>>(
        u_msg_bf, csr_i, offend_i, i_part, item_table, V1_bf, Vf_bf);

    // attention pooling + output (MFMA)
    phase2_kernel<<<BATCH / 4, 256, 0, stream>>>(user_table, Vf_bf, Watt, Wb, Wagg,
                                                 uidx, ctx, out);
}

// Round 2
// 258.494 us; speedup vs baseline: 1.4397x; 1.4397x over previous
//
#include <hip/hip_runtime.h>

#define N_USERS 100000
#define N_ITEMS 50001
#define N_EDGES 1000000
#define D 64
#define BATCH 4096
#define MAXLEN 50

// coarse buckets, fixed capacity (no hist/scan): counts ~N(2560,51), CAP=3072 is 10 sigma
#define SHU 8
#define SHI 7
#define NBU ((N_USERS + 255) >> 8)    // 391
#define NBI ((N_ITEMS + 127) >> 7)    // 391
#define CAP 3072
#define BEPB 8192
#define BBLOCKS ((N_EDGES + BEPB - 1) / BEPB) // 123

typedef __attribute__((ext_vector_type(8))) short short8;
typedef __attribute__((ext_vector_type(4))) float f32x4;

// ---------- bf16 helpers ----------
__device__ __forceinline__ float bf_lo(unsigned u) { return __uint_as_float(u << 16); }
__device__ __forceinline__ float bf_hi(unsigned u) { return __uint_as_float(u & 0xffff0000u); }
__device__ __forceinline__ float bf_s(unsigned short s) { return __uint_as_float(((unsigned)s) << 16); }
__device__ __forceinline__ unsigned bf_pack2(float a, float b) {
    unsigned ba = __float_as_uint(a);
    unsigned bb = __float_as_uint(b);
    ba += 0x7fffu + ((ba >> 16) & 1u);
    bb += 0x7fffu + ((bb >> 16) & 1u);
    return (ba >> 16) | (bb & 0xffff0000u);
}
__device__ __forceinline__ float fast_tanh(float x) {
    float e = __expf(2.0f * x);
    return 1.0f - 2.0f * __builtin_amdgcn_rcpf(e + 1.0f);
}

// ---------------- fp32 -> bf16 table convert ----------------
__global__ __launch_bounds__(256) void convert_kernel(
    const float* __restrict__ src, unsigned* __restrict__ dst, int npairs)
{
    int i = blockIdx.x * 256 + threadIdx.x;
    if (i < npairs) {
        float2 f = ((const float2*)src)[i];
        dst[i] = bf_pack2(f.x, f.y);
    }
}

// ---------------- pass A: bin edges into fixed-capacity buckets ----------------
// staged entry (8 B): .x = (row_local << 16) | q_val, .y = src_idx
// 512 threads; bucket b region = [b*CAP, b*CAP+cnt)
__global__ __launch_bounds__(512) void bin_kernel(
    const int* __restrict__ eu, const int* __restrict__ ei,
    const float* __restrict__ ev_uv, const float* __restrict__ ev_vu,
    int* __restrict__ gcur_u, int* __restrict__ gcur_i,
    int2* __restrict__ staged_u, int2* __restrict__ staged_i)
{
    __shared__ int hist[NBU];
    __shared__ int runbase[NBU];
    __shared__ unsigned short rank[BEPB];
    int tid = threadIdx.x;
    int dir_i = (blockIdx.x >= BBLOCKS) ? 1 : 0;
    int blk = blockIdx.x - (dir_i ? BBLOCKS : 0);
    const int* erow = dir_i ? ei : eu;
    const int* esrc = dir_i ? eu : ei;
    const float* eval = dir_i ? ev_vu : ev_uv;
    int* gcur = dir_i ? gcur_i : gcur_u;
    int2* staged = dir_i ? staged_i : staged_u;
    const int shift = dir_i ? SHI : SHU;
    const float qs = dir_i ? 32767.0f : 65535.0f;
    const int rlmask = dir_i ? 127 : 255;
    const int nb = dir_i ? NBI : NBU;

    for (int i = tid; i < nb; i += 512) hist[i] = 0;
    __syncthreads();
    int e0 = blk * BEPB;
    for (int k = 0; k < BEPB / 512; ++k) {
        int slot = k * 512 + tid;
        int e = e0 + slot;
        if (e < N_EDGES)
            rank[slot] = (unsigned short)atomicAdd(&hist[erow[e] >> shift], 1);
    }
    __syncthreads();
    for (int i = tid; i < nb; i += 512) {
        int cn = hist[i];
        runbase[i] = cn ? (i * CAP + atomicAdd(&gcur[i], cn)) : 0;
    }
    __syncthreads();
    for (int k = 0; k < BEPB / 512; ++k) {
        int slot = k * 512 + tid;
        int e = e0 + slot;
        if (e < N_EDGES) {
            int row = erow[e];
            unsigned q = (unsigned)(fminf(fmaxf(eval[e], 0.0f), 1.0f) * qs + 0.5f);
            int2 en;
            en.x = (int)((unsigned)(row & rlmask) << 16 | q);
            en.y = esrc[e];
            staged[runbase[row >> shift] + rank[slot]] = en;
        }
    }
}

// ---------------- pass B: place within bucket ----------------
__global__ __launch_bounds__(256) void place_kernel(
    const int2* __restrict__ staged_u, const int2* __restrict__ staged_i,
    const int* __restrict__ gcur_u, const int* __restrict__ gcur_i,
    unsigned* __restrict__ csr_u, unsigned* __restrict__ csr_i,
    int2* __restrict__ offend_u, int2* __restrict__ offend_i)
{
    __shared__ int cnt[256];
    __shared__ int s[256];
    __shared__ int cur[256];
    int tid = threadIdx.x;
    int dir_i = (blockIdx.x >= NBU) ? 1 : 0;
    int b = blockIdx.x - (dir_i ? NBU : 0);
    const int2* staged = dir_i ? staged_i : staged_u;
    const int* gcur = dir_i ? gcur_i : gcur_u;
    unsigned* csr = dir_i ? csr_i : csr_u;
    int2* offend = dir_i ? offend_i : offend_u;
    const int NR = dir_i ? 128 : 256;
    const int nrows = dir_i ? N_ITEMS : N_USERS;
    const int idxbits = dir_i ? 17 : 16;

    int sb = b * CAP;
    int eb = sb + gcur[b];
    if (tid < NR) cnt[tid] = 0;
    __syncthreads();
    for (int idx = sb + tid; idx < eb; idx += 256) {
        int rl = ((unsigned)staged[idx].x) >> 16;
        atomicAdd(&cnt[rl], 1);
    }
    __syncthreads();
    int c = (tid < NR) ? cnt[tid] : 0;
    s[tid] = c;
    __syncthreads();
    for (int off = 1; off < 256; off <<= 1) {
        int v = (tid >= off) ? s[tid - off] : 0;
        __syncthreads();
        s[tid] += v;
        __syncthreads();
    }
    int excl = s[tid] - c;
    int row = b * NR + tid;
    if (tid < NR && row < nrows) {
        int2 oe; oe.x = sb + excl; oe.y = sb + excl + c;
        offend[row] = oe;
    }
    if (tid < NR) cur[tid] = sb + excl;
    __syncthreads();
    for (int idx = sb + tid; idx < eb; idx += 256) {
        int2 en = staged[idx];
        unsigned w0 = (unsigned)en.x;
        int rl = w0 >> 16;
        unsigned q = w0 & 0xFFFFu;
        int pos = atomicAdd(&cur[rl], 1);
        csr[pos] = (q << idxbits) | (unsigned)en.y;
    }
}

// ---------------- gather spmm: eighth-wave (8 lanes x 16B) per ROW ----------------
// Each 8-lane group owns one output row; lane covers a 16-B (uint4) column slice.
// Per wave-instr: row-load fetches 8 rows x 128 B = 1 KB (coalescing sweet spot);
// one shfl broadcast serves 8 edges. Numerically identical to the 16-lane version.
template<int IDXBITS>
__device__ __forceinline__ void gather_row_g8(
    const unsigned* __restrict__ src, const unsigned* __restrict__ csr,
    int o, int e, int c4, int g,
    float& A0, float& A1, float& A2, float& A3,
    float& A4, float& A5, float& A6, float& A7)
{
    constexpr unsigned MASK = (1u << IDXBITS) - 1u;
    constexpr float SCALE = 1.0f / (float)((1u << (32 - IDXBITS)) - 1u);
    float a0 = 0.f, a1 = 0.f, a2 = 0.f, a3 = 0.f;
    float a4 = 0.f, a5 = 0.f, a6 = 0.f, a7 = 0.f;
    for (int base = o; base < e; base += 8) {
        int n = min(8, e - base);
        unsigned word = 0;
        if (c4 < n) word = __builtin_nontemporal_load(csr + base + c4);
#pragma unroll 4
        for (int j = 0; j < n; ++j) {
            unsigned wj = (unsigned)__shfl((int)word, 8 * g + j, 64);
            int r = (int)(wj & MASK);
            float v = (float)(wj >> IDXBITS) * SCALE;
            uint4 u4 = *(const uint4*)(src + (size_t)r * 32 + 4 * c4);
            a0 = fmaf(v, bf_lo(u4.x), a0);
            a1 = fmaf(v, bf_hi(u4.x), a1);
            a2 = fmaf(v, bf_lo(u4.y), a2);
            a3 = fmaf(v, bf_hi(u4.y), a3);
            a4 = fmaf(v, bf_lo(u4.z), a4);
            a5 = fmaf(v, bf_hi(u4.z), a5);
            a6 = fmaf(v, bf_lo(u4.w), a6);
            a7 = fmaf(v, bf_hi(u4.w), a7);
        }
    }
    A0 = a0; A1 = a1; A2 = a2; A3 = a3;
    A4 = a4; A5 = a5; A6 = a6; A7 = a7;
}

template<int IDXBITS>
__global__ __launch_bounds__(256) void gather_bf_kernel(
    const unsigned* __restrict__ src, const unsigned* __restrict__ csr,
    const int2* __restrict__ offend,
    unsigned* __restrict__ dst, int nrows)
{
    int gw = (blockIdx.x * 256 + threadIdx.x) >> 6;
    int lane = threadIdx.x & 63;
    int g = lane >> 3, c4 = lane & 7;
    int row = gw * 8 + g;
    int2 oe = (row < nrows) ? offend[row] : make_int2(0, 0);
    float a0, a1, a2, a3, a4, a5, a6, a7;
    gather_row_g8<IDXBITS>(src, csr, oe.x, oe.y, c4, g,
                           a0, a1, a2, a3, a4, a5, a6, a7);
    if (row < nrows) {
        uint4 o4;
        o4.x = bf_pack2(a0, a1);
        o4.y = bf_pack2(a2, a3);
        o4.z = bf_pack2(a4, a5);
        o4.w = bf_pack2(a6, a7);
        *((uint4*)(dst + (size_t)row * 32) + c4) = o4;
    }
}

// final: V2-gather fused with Vf = (V0 + V1 + V2)/3 + V0; Vf packed bf16
__global__ __launch_bounds__(256) void gather_final_bf_kernel(
    const unsigned* __restrict__ src, const unsigned* __restrict__ csr,
    const int2* __restrict__ offend,
    const float* __restrict__ V0, const unsigned* __restrict__ V1bf,
    unsigned* __restrict__ Vf_bf)
{
    int gw = (blockIdx.x * 256 + threadIdx.x) >> 6;
    int lane = threadIdx.x & 63;
    int g = lane >> 3, c4 = lane & 7;
    int row = gw * 8 + g;
    int2 oe = (row < N_ITEMS) ? offend[row] : make_int2(0, 0);
    float a0, a1, a2, a3, a4, a5, a6, a7;
    gather_row_g8<17>(src, csr, oe.x, oe.y, c4, g,
                      a0, a1, a2, a3, a4, a5, a6, a7);
    if (row < N_ITEMS) {
        float4 v0a = *((const float4*)(V0 + (size_t)row * 64) + 2 * c4);
        float4 v0b = *((const float4*)(V0 + (size_t)row * 64) + 2 * c4 + 1);
        uint4 u1 = *((const uint4*)(V1bf + (size_t)row * 32) + c4);
        float r0 = (v0a.x + bf_lo(u1.x) + a0) * (1.0f / 3.0f) + v0a.x;
        float r1 = (v0a.y + bf_hi(u1.x) + a1) * (1.0f / 3.0f) + v0a.y;
        float r2 = (v0a.z + bf_lo(u1.y) + a2) * (1.0f / 3.0f) + v0a.z;
        float r3 = (v0a.w + bf_hi(u1.y) + a3) * (1.0f / 3.0f) + v0a.w;
        float r4 = (v0b.x + bf_lo(u1.z) + a4) * (1.0f / 3.0f) + v0b.x;
        float r5 = (v0b.y + bf_hi(u1.z) + a5) * (1.0f / 3.0f) + v0b.y;
        float r6 = (v0b.z + bf_lo(u1.w) + a6) * (1.0f / 3.0f) + v0b.z;
        float r7 = (v0b.w + bf_hi(u1.w) + a7) * (1.0f / 3.0f) + v0b.w;
        uint4 o4;
        o4.x = bf_pack2(r0, r1);
        o4.y = bf_pack2(r2, r3);
        o4.z = bf_pack2(r4, r5);
        o4.w = bf_pack2(r6, r7);
        *((uint4*)(Vf_bf + (size_t)row * 32) + c4) = o4;
    }
}

// ---------------- attention pooling via MFMA (round-8, verified) ----------------
__global__ __launch_bounds__(256) void phase2_kernel(
    const float* __restrict__ user_table, const unsigned* __restrict__ Vf_bf,
    const float* __restrict__ Watt, const float* __restrict__ Wb,
    const float* __restrict__ Wagg, const int* __restrict__ uidx,
    const int* __restrict__ ctx, float* __restrict__ out)
{
    __shared__ __align__(16) unsigned seq[4][64 * 36];
    __shared__ unsigned short wgT[64 * 72];
    __shared__ __align__(16) float idrow[4][64];
    __shared__ float attn_l[4][64];
    __shared__ float pooled_l[4][64];

    const int tid = threadIdx.x;
    const int w = tid >> 6;
    const int lane = tid & 63;
    const int q = lane >> 4;
    const int n = lane & 15;
    const int b = blockIdx.x * 4 + w;

    for (int i = tid; i < 64 * 64; i += 256) {
        int e = i >> 6, d = i & 63;
        unsigned bb = __float_as_uint(Wagg[i]);
        bb += 0x7fffu + ((bb >> 16) & 1u);
        wgT[d * 72 + e] = (unsigned short)(bb >> 16);
    }
    __syncthreads();

    short8 wa_f[4][2];
#pragma unroll
    for (int et = 0; et < 4; ++et)
#pragma unroll
        for (int ks = 0; ks < 2; ++ks) {
            const float* rp = Watt + (size_t)(16 * et + n) * 64 + 32 * ks + 8 * q;
            float4 f0 = *(const float4*)rp;
            float4 f1 = *(const float4*)(rp + 4);
            union { short8 s; unsigned u[4]; } t;
            t.u[0] = bf_pack2(f0.x, f0.y);
            t.u[1] = bf_pack2(f0.z, f0.w);
            t.u[2] = bf_pack2(f1.x, f1.y);
            t.u[3] = bf_pack2(f1.z, f1.w);
            wa_f[et][ks] = t.s;
        }
    f32x4 biasv[4];
#pragma unroll
    for (int et = 0; et < 4; ++et)
        biasv[et] = *(const f32x4*)(Wb + 16 * et + 4 * q);
    short8 ones8;
#pragma unroll
    for (int j = 0; j < 8; ++j) ones8[j] = (short)0x3F80;

    int uid = uidx[b];
    idrow[w][lane] = user_table[(size_t)uid * 64 + lane];
    f32x4 idv[4];
#pragma unroll
    for (int et = 0; et < 4; ++et)
        idv[et] = *(f32x4*)&idrow[w][16 * et + 4 * q];

    int ci = (lane < MAXLEN) ? ctx[b * MAXLEN + lane] : 0;
#pragma unroll 5
    for (int it = 0; it < 25; ++it) {
        int l = 2 * it + (lane >> 5);
        int cc = lane & 31;
        int rsrc = __shfl(ci, l, 64);
        seq[w][l * 36 + cc] = Vf_bf[(size_t)rsrc * 32 + cc];
    }

    float xs[4];
#pragma unroll
    for (int lt = 0; lt < 4; ++lt) {
        union { short8 s; uint4 u; } B0, B1;
        B0.u = *(const uint4*)&seq[w][(16 * lt + n) * 36 + 4 * q];
        B1.u = *(const uint4*)&seq[w][(16 * lt + n) * 36 + 16 + 4 * q];

        f32x4 rsum = {0.f, 0.f, 0.f, 0.f};
        rsum = __builtin_amdgcn_mfma_f32_16x16x32_bf16(ones8, B0.s, rsum, 0, 0, 0);
        rsum = __builtin_amdgcn_mfma_f32_16x16x32_bf16(ones8, B1.s, rsum, 0, 0, 0);
        float rsv = rsum[0];

        float xacc = 0.0f;
#pragma unroll
        for (int et = 0; et < 4; ++et) {
            f32x4 a = {0.f, 0.f, 0.f, 0.f};
            a = __builtin_amdgcn_mfma_f32_16x16x32_bf16(wa_f[et][0], B0.s, a, 0, 0, 0);
            a = __builtin_amdgcn_mfma_f32_16x16x32_bf16(wa_f[et][1], B1.s, a, 0, 0, 0);
#pragma unroll
            for (int r = 0; r < 4; ++r) {
                float t = fast_tanh(a[r] + biasv[et][r]);
                xacc = fmaf(t, idv[et][r], xacc);
            }
        }
        xacc += __shfl_xor(xacc, 16, 64);
        xacc += __shfl_xor(xacc, 32, 64);
        xs[lt] = (rsv == 0.0f) ? 0.0f : xacc;
    }

    float ex[4];
    float tot = 0.0f;
#pragma unroll
    for (int lt = 0; lt < 4; ++lt) {
        int l = 16 * lt + n;
        ex[lt] = (l < MAXLEN) ? __expf(xs[lt]) : 0.0f;
        tot += ex[lt];
    }
    tot += __shfl_xor(tot, 1, 64);
    tot += __shfl_xor(tot, 2, 64);
    tot += __shfl_xor(tot, 4, 64);
    tot += __shfl_xor(tot, 8, 64);
    float inv = 1.0f / (tot + 1e-12f);
    if (lane < 16) {
#pragma unroll
        for (int lt = 0; lt < 4; ++lt)
            attn_l[w][16 * lt + lane] = ex[lt] * inv;
    }

    float pooled = 0.0f;
    for (int l = 0; l < MAXLEN; ++l) {
        float a = attn_l[w][l];
        unsigned uu = seq[w][l * 36 + (lane >> 1)];
        float sv = (lane & 1) ? bf_hi(uu) : bf_lo(uu);
        pooled = fmaf(a, sv, pooled);
    }
    pooled_l[w][lane] = pooled;

    float o = 0.0f;
#pragma unroll 8
    for (int d = 0; d < 64; ++d) {
        float pv = pooled_l[w][d];
        float wv = bf_s(wgT[d * 72 + lane]);
        o = fmaf(pv, wv, o);
    }
    out[(size_t)b * 64 + lane] = 0.5f * idrow[w][lane] + 0.5f * o;
}

// ---------------- launch ----------------

extern "C" void kernel_launch(void* const* d_in, const int* in_sizes, int n_in,
                              void* d_out, int out_size, void* d_ws, size_t ws_size,
                              hipStream_t stream)
{
    const float* user_table = (const float*)d_in[0];
    const float* item_table = (const float*)d_in[1];
    const float* ev_uv      = (const float*)d_in[2];
    const float* ev_vu      = (const float*)d_in[3];
    const float* Watt       = (const float*)d_in[4];
    const float* Wb         = (const float*)d_in[5];
    const float* Wagg       = (const float*)d_in[6];
    const int*   edge_u     = (const int*)d_in[7];
    const int*   edge_i     = (const int*)d_in[8];
    const int*   uidx       = (const int*)d_in[9];
    const int*   ctx        = (const int*)d_in[10];
    float* out = (float*)d_out;

    const size_t NCAP = (size_t)NBU * CAP;  // 1201152 entries per direction

    // workspace layout (~56 MB)
    char* p = (char*)d_ws;
    unsigned* it_bf    = (unsigned*)p; p += (size_t)N_ITEMS * 32 * 4;   // 6.4 MB
    unsigned* u_msg_bf = (unsigned*)p; p += (size_t)N_USERS * 32 * 4;   // 12.8 MB
    unsigned* V1_bf    = (unsigned*)p; p += (size_t)N_ITEMS * 32 * 4;   // 6.4 MB
    // staged region (19.2 MB) — Vf_bf (6.4 MB) aliases it; staged dead by then
    char*     Sreg     = p;            p += NCAP * 8 * 2;               // 19.2 MB
    int2*     staged_u = (int2*)Sreg;
    int2*     staged_i = (int2*)(Sreg + NCAP * 8);
    unsigned* Vf_bf    = (unsigned*)Sreg;
    unsigned* csr_u    = (unsigned*)p; p += NCAP * 4;                   // 4.8 MB
    unsigned* csr_i    = (unsigned*)p; p += NCAP * 4;                   // 4.8 MB
    int2*     offend_u = (int2*)p;     p += (size_t)N_USERS * 8;        // 0.8 MB
    int2*     offend_i = (int2*)p;     p += (size_t)N_ITEMS * 8;        // 0.4 MB
    int*      gcur_u   = (int*)p;      p += NBU * 4;                    // contiguous
    int*      gcur_i   = (int*)p;      p += NBI * 4;                    //  pair

    // zero within-bucket cursors
    hipMemsetAsync(gcur_u, 0, (NBU + NBI) * 4, stream);

    convert_kernel<<<(N_ITEMS * 32 + 255) / 256, 256, 0, stream>>>(
        item_table, it_bf, N_ITEMS * 32);

    bin_kernel<<<2 * BBLOCKS, 512, 0, stream>>>(edge_u, edge_i, ev_uv, ev_vu,
                                                gcur_u, gcur_i, staged_u, staged_i);
    place_kernel<<<NBU + NBI, 256, 0, stream>>>(staged_u, staged_i, gcur_u, gcur_i,
                                                csr_u, csr_i, offend_u, offend_i);

    // 32 rows per block (4 waves x 8 eighth-wave rows)
    const int ublocks = (N_USERS + 31) / 32;
    const int iblocks = (N_ITEMS + 31) / 32;

    // layer 1
    gather_bf_kernel<16><<<ublocks, 256, 0, stream>>>(it_bf, csr_u, offend_u, u_msg_bf, N_USERS);
    gather_bf_kernel<17><<<iblocks, 256, 0, stream>>>(u_msg_bf, csr_i, offend_i, V1_bf, N_ITEMS);
    // layer 2 (+ fused combine -> Vf bf16; aliases dead staged region)
    gather_bf_kernel<16><<<ublocks, 256, 0, stream>>>(V1_bf, csr_u, offend_u, u_msg_bf, N_USERS);
    gather_final_bf_kernel<<<iblocks, 256, 0, stream>>>(u_msg_bf, csr_i, offend_i,
                                                        item_table, V1_bf, Vf_bf);

    // attention pooling + output (MFMA)
    phase2_kernel<<<BATCH / 4, 256, 0, stream>>>(user_table, Vf_bf, Watt, Wb, Wagg,
                                                 uidx, ctx, out);
}

// Round 3
// 247.148 us; speedup vs baseline: 1.5058x; 1.0459x over previous
//
#include <hip/hip_runtime.h>

#define N_USERS 100000
#define N_ITEMS 50001
#define N_EDGES 1000000
#define D 64
#define BATCH 4096
#define MAXLEN 50

// coarse buckets, fixed capacity (no hist/scan): counts ~N(2560,51), CAP=3072 is 10 sigma
#define SHU 8
#define SHI 7
#define NBU ((N_USERS + 255) >> 8)    // 391
#define NBI ((N_ITEMS + 127) >> 7)    // 391
#define CAP 3072
#define BEPB 8192
#define BBLOCKS ((N_EDGES + BEPB - 1) / BEPB) // 123

typedef __attribute__((ext_vector_type(8))) short short8;
typedef __attribute__((ext_vector_type(4))) float f32x4;

// ---------- bf16 helpers ----------
__device__ __forceinline__ float bf_lo(unsigned u) { return __uint_as_float(u << 16); }
__device__ __forceinline__ float bf_hi(unsigned u) { return __uint_as_float(u & 0xffff0000u); }
__device__ __forceinline__ float bf_s(unsigned short s) { return __uint_as_float(((unsigned)s) << 16); }
__device__ __forceinline__ unsigned bf_pack2(float a, float b) {
    unsigned ba = __float_as_uint(a);
    unsigned bb = __float_as_uint(b);
    ba += 0x7fffu + ((ba >> 16) & 1u);
    bb += 0x7fffu + ((bb >> 16) & 1u);
    return (ba >> 16) | (bb & 0xffff0000u);
}
__device__ __forceinline__ float fast_tanh(float x) {
    float e = __expf(2.0f * x);
    return 1.0f - 2.0f * __builtin_amdgcn_rcpf(e + 1.0f);
}

// ---------------- fp32 -> bf16 table convert ----------------
__global__ __launch_bounds__(256) void convert_kernel(
    const float* __restrict__ src, unsigned* __restrict__ dst, int npairs)
{
    int i = blockIdx.x * 256 + threadIdx.x;
    if (i < npairs) {
        float2 f = ((const float2*)src)[i];
        dst[i] = bf_pack2(f.x, f.y);
    }
}

// ---------------- pass A: bin edges into fixed-capacity buckets ----------------
// staged entry (8 B): .x = (row_local << 16) | q_val, .y = src_idx
// 512 threads; bucket b region = [b*CAP, b*CAP+cnt)
__global__ __launch_bounds__(512) void bin_kernel(
    const int* __restrict__ eu, const int* __restrict__ ei,
    const float* __restrict__ ev_uv, const float* __restrict__ ev_vu,
    int* __restrict__ gcur_u, int* __restrict__ gcur_i,
    int2* __restrict__ staged_u, int2* __restrict__ staged_i)
{
    __shared__ int hist[NBU];
    __shared__ int runbase[NBU];
    __shared__ unsigned short rank[BEPB];
    int tid = threadIdx.x;
    int dir_i = (blockIdx.x >= BBLOCKS) ? 1 : 0;
    int blk = blockIdx.x - (dir_i ? BBLOCKS : 0);
    const int* erow = dir_i ? ei : eu;
    const int* esrc = dir_i ? eu : ei;
    const float* eval = dir_i ? ev_vu : ev_uv;
    int* gcur = dir_i ? gcur_i : gcur_u;
    int2* staged = dir_i ? staged_i : staged_u;
    const int shift = dir_i ? SHI : SHU;
    const float qs = dir_i ? 32767.0f : 65535.0f;
    const int rlmask = dir_i ? 127 : 255;
    const int nb = dir_i ? NBI : NBU;

    for (int i = tid; i < nb; i += 512) hist[i] = 0;
    __syncthreads();
    int e0 = blk * BEPB;
    for (int k = 0; k < BEPB / 512; ++k) {
        int slot = k * 512 + tid;
        int e = e0 + slot;
        if (e < N_EDGES)
            rank[slot] = (unsigned short)atomicAdd(&hist[erow[e] >> shift], 1);
    }
    __syncthreads();
    for (int i = tid; i < nb; i += 512) {
        int cn = hist[i];
        runbase[i] = cn ? (i * CAP + atomicAdd(&gcur[i], cn)) : 0;
    }
    __syncthreads();
    for (int k = 0; k < BEPB / 512; ++k) {
        int slot = k * 512 + tid;
        int e = e0 + slot;
        if (e < N_EDGES) {
            int row = erow[e];
            unsigned q = (unsigned)(fminf(fmaxf(eval[e], 0.0f), 1.0f) * qs + 0.5f);
            int2 en;
            en.x = (int)((unsigned)(row & rlmask) << 16 | q);
            en.y = esrc[e];
            staged[runbase[row >> shift] + rank[slot]] = en;
        }
    }
}

// ---------------- pass B: place within bucket ----------------
__global__ __launch_bounds__(256) void place_kernel(
    const int2* __restrict__ staged_u, const int2* __restrict__ staged_i,
    const int* __restrict__ gcur_u, const int* __restrict__ gcur_i,
    unsigned* __restrict__ csr_u, unsigned* __restrict__ csr_i,
    int2* __restrict__ offend_u, int2* __restrict__ offend_i)
{
    __shared__ int cnt[256];
    __shared__ int s[256];
    __shared__ int cur[256];
    int tid = threadIdx.x;
    int dir_i = (blockIdx.x >= NBU) ? 1 : 0;
    int b = blockIdx.x - (dir_i ? NBU : 0);
    const int2* staged = dir_i ? staged_i : staged_u;
    const int* gcur = dir_i ? gcur_i : gcur_u;
    unsigned* csr = dir_i ? csr_i : csr_u;
    int2* offend = dir_i ? offend_i : offend_u;
    const int NR = dir_i ? 128 : 256;
    const int nrows = dir_i ? N_ITEMS : N_USERS;
    const int idxbits = dir_i ? 17 : 16;

    int sb = b * CAP;
    int eb = sb + gcur[b];
    if (tid < NR) cnt[tid] = 0;
    __syncthreads();
    for (int idx = sb + tid; idx < eb; idx += 256) {
        int rl = ((unsigned)staged[idx].x) >> 16;
        atomicAdd(&cnt[rl], 1);
    }
    __syncthreads();
    int c = (tid < NR) ? cnt[tid] : 0;
    s[tid] = c;
    __syncthreads();
    for (int off = 1; off < 256; off <<= 1) {
        int v = (tid >= off) ? s[tid - off] : 0;
        __syncthreads();
        s[tid] += v;
        __syncthreads();
    }
    int excl = s[tid] - c;
    int row = b * NR + tid;
    if (tid < NR && row < nrows) {
        int2 oe; oe.x = sb + excl; oe.y = sb + excl + c;
        offend[row] = oe;
    }
    if (tid < NR) cur[tid] = sb + excl;
    __syncthreads();
    for (int idx = sb + tid; idx < eb; idx += 256) {
        int2 en = staged[idx];
        unsigned w0 = (unsigned)en.x;
        int rl = w0 >> 16;
        unsigned q = w0 & 0xFFFFu;
        int pos = atomicAdd(&cur[rl], 1);
        csr[pos] = (q << idxbits) | (unsigned)en.y;
    }
}

// ---------------- gather spmm: eighth-wave (8 lanes x 16B) per ROW ----------------
// Compile-time 8-iteration chunk with per-edge predication (invalid -> r=0, v=0;
// row 0 is real finite data so fmaf(0,x,a)==a exactly). All 8 row-loads are
// issued before any consumption -> MLP=8 per wave (the previous runtime-bound
// loop serialized to 1 load in flight per wave).
template<int IDXBITS>
__device__ __forceinline__ void gather_row_g8(
    const unsigned* __restrict__ src, const unsigned* __restrict__ csr,
    int o, int e, int c4, int g,
    float& A0, float& A1, float& A2, float& A3,
    float& A4, float& A5, float& A6, float& A7)
{
    constexpr unsigned MASK = (1u << IDXBITS) - 1u;
    constexpr float SCALE = 1.0f / (float)((1u << (32 - IDXBITS)) - 1u);
    float a0 = 0.f, a1 = 0.f, a2 = 0.f, a3 = 0.f;
    float a4 = 0.f, a5 = 0.f, a6 = 0.f, a7 = 0.f;
    for (int base = o; base < e; base += 8) {
        // may over-read within the padded bucket region (CAP-sized, allocated);
        // consumption is predicated below.
        unsigned word = __builtin_nontemporal_load(csr + base + c4);
        uint4 u4[8];
        float v[8];
#pragma unroll
        for (int j = 0; j < 8; ++j) {
            unsigned wj = (unsigned)__shfl((int)word, 8 * g + j, 64);
            bool valid = (base + j) < e;
            int r = valid ? (int)(wj & MASK) : 0;
            v[j] = valid ? (float)(wj >> IDXBITS) * SCALE : 0.0f;
            u4[j] = *(const uint4*)(src + (size_t)r * 32 + 4 * c4);
        }
#pragma unroll
        for (int j = 0; j < 8; ++j) {
            a0 = fmaf(v[j], bf_lo(u4[j].x), a0);
            a1 = fmaf(v[j], bf_hi(u4[j].x), a1);
            a2 = fmaf(v[j], bf_lo(u4[j].y), a2);
            a3 = fmaf(v[j], bf_hi(u4[j].y), a3);
            a4 = fmaf(v[j], bf_lo(u4[j].z), a4);
            a5 = fmaf(v[j], bf_hi(u4[j].z), a5);
            a6 = fmaf(v[j], bf_lo(u4[j].w), a6);
            a7 = fmaf(v[j], bf_hi(u4[j].w), a7);
        }
    }
    A0 = a0; A1 = a1; A2 = a2; A3 = a3;
    A4 = a4; A5 = a5; A6 = a6; A7 = a7;
}

template<int IDXBITS>
__global__ __launch_bounds__(256) void gather_bf_kernel(
    const unsigned* __restrict__ src, const unsigned* __restrict__ csr,
    const int2* __restrict__ offend,
    unsigned* __restrict__ dst, int nrows)
{
    int gw = (blockIdx.x * 256 + threadIdx.x) >> 6;
    int lane = threadIdx.x & 63;
    int g = lane >> 3, c4 = lane & 7;
    int row = gw * 8 + g;
    int2 oe = (row < nrows) ? offend[row] : make_int2(0, 0);
    float a0, a1, a2, a3, a4, a5, a6, a7;
    gather_row_g8<IDXBITS>(src, csr, oe.x, oe.y, c4, g,
                           a0, a1, a2, a3, a4, a5, a6, a7);
    if (row < nrows) {
        uint4 o4;
        o4.x = bf_pack2(a0, a1);
        o4.y = bf_pack2(a2, a3);
        o4.z = bf_pack2(a4, a5);
        o4.w = bf_pack2(a6, a7);
        *((uint4*)(dst + (size_t)row * 32) + c4) = o4;
    }
}

// final: V2-gather fused with Vf = (V0 + V1 + V2)/3 + V0; Vf packed bf16
__global__ __launch_bounds__(256) void gather_final_bf_kernel(
    const unsigned* __restrict__ src, const unsigned* __restrict__ csr,
    const int2* __restrict__ offend,
    const float* __restrict__ V0, const unsigned* __restrict__ V1bf,
    unsigned* __restrict__ Vf_bf)
{
    int gw = (blockIdx.x * 256 + threadIdx.x) >> 6;
    int lane = threadIdx.x & 63;
    int g = lane >> 3, c4 = lane & 7;
    int row = gw * 8 + g;
    int2 oe = (row < N_ITEMS) ? offend[row] : make_int2(0, 0);
    float a0, a1, a2, a3, a4, a5, a6, a7;
    gather_row_g8<17>(src, csr, oe.x, oe.y, c4, g,
                      a0, a1, a2, a3, a4, a5, a6, a7);
    if (row < N_ITEMS) {
        float4 v0a = *((const float4*)(V0 + (size_t)row * 64) + 2 * c4);
        float4 v0b = *((const float4*)(V0 + (size_t)row * 64) + 2 * c4 + 1);
        uint4 u1 = *((const uint4*)(V1bf + (size_t)row * 32) + c4);
        float r0 = (v0a.x + bf_lo(u1.x) + a0) * (1.0f / 3.0f) + v0a.x;
        float r1 = (v0a.y + bf_hi(u1.x) + a1) * (1.0f / 3.0f) + v0a.y;
        float r2 = (v0a.z + bf_lo(u1.y) + a2) * (1.0f / 3.0f) + v0a.z;
        float r3 = (v0a.w + bf_hi(u1.y) + a3) * (1.0f / 3.0f) + v0a.w;
        float r4 = (v0b.x + bf_lo(u1.z) + a4) * (1.0f / 3.0f) + v0b.x;
        float r5 = (v0b.y + bf_hi(u1.z) + a5) * (1.0f / 3.0f) + v0b.y;
        float r6 = (v0b.z + bf_lo(u1.w) + a6) * (1.0f / 3.0f) + v0b.z;
        float r7 = (v0b.w + bf_hi(u1.w) + a7) * (1.0f / 3.0f) + v0b.w;
        uint4 o4;
        o4.x = bf_pack2(r0, r1);
        o4.y = bf_pack2(r2, r3);
        o4.z = bf_pack2(r4, r5);
        o4.w = bf_pack2(r6, r7);
        *((uint4*)(Vf_bf + (size_t)row * 32) + c4) = o4;
    }
}

// ---------------- attention pooling via MFMA (round-8, verified) ----------------
__global__ __launch_bounds__(256) void phase2_kernel(
    const float* __restrict__ user_table, const unsigned* __restrict__ Vf_bf,
    const float* __restrict__ Watt, const float* __restrict__ Wb,
    const float* __restrict__ Wagg, const int* __restrict__ uidx,
    const int* __restrict__ ctx, float* __restrict__ out)
{
    __shared__ __align__(16) unsigned seq[4][64 * 36];
    __shared__ unsigned short wgT[64 * 72];
    __shared__ __align__(16) float idrow[4][64];
    __shared__ float attn_l[4][64];
    __shared__ float pooled_l[4][64];

    const int tid = threadIdx.x;
    const int w = tid >> 6;
    const int lane = tid & 63;
    const int q = lane >> 4;
    const int n = lane & 15;
    const int b = blockIdx.x * 4 + w;

    for (int i = tid; i < 64 * 64; i += 256) {
        int e = i >> 6, d = i & 63;
        unsigned bb = __float_as_uint(Wagg[i]);
        bb += 0x7fffu + ((bb >> 16) & 1u);
        wgT[d * 72 + e] = (unsigned short)(bb >> 16);
    }
    __syncthreads();

    short8 wa_f[4][2];
#pragma unroll
    for (int et = 0; et < 4; ++et)
#pragma unroll
        for (int ks = 0; ks < 2; ++ks) {
            const float* rp = Watt + (size_t)(16 * et + n) * 64 + 32 * ks + 8 * q;
            float4 f0 = *(const float4*)rp;
            float4 f1 = *(const float4*)(rp + 4);
            union { short8 s; unsigned u[4]; } t;
            t.u[0] = bf_pack2(f0.x, f0.y);
            t.u[1] = bf_pack2(f0.z, f0.w);
            t.u[2] = bf_pack2(f1.x, f1.y);
            t.u[3] = bf_pack2(f1.z, f1.w);
            wa_f[et][ks] = t.s;
        }
    f32x4 biasv[4];
#pragma unroll
    for (int et = 0; et < 4; ++et)
        biasv[et] = *(const f32x4*)(Wb + 16 * et + 4 * q);
    short8 ones8;
#pragma unroll
    for (int j = 0; j < 8; ++j) ones8[j] = (short)0x3F80;

    int uid = uidx[b];
    idrow[w][lane] = user_table[(size_t)uid * 64 + lane];
    f32x4 idv[4];
#pragma unroll
    for (int et = 0; et < 4; ++et)
        idv[et] = *(f32x4*)&idrow[w][16 * et + 4 * q];

    int ci = (lane < MAXLEN) ? ctx[b * MAXLEN + lane] : 0;
#pragma unroll 5
    for (int it = 0; it < 25; ++it) {
        int l = 2 * it + (lane >> 5);
        int cc = lane & 31;
        int rsrc = __shfl(ci, l, 64);
        seq[w][l * 36 + cc] = Vf_bf[(size_t)rsrc * 32 + cc];
    }

    float xs[4];
#pragma unroll
    for (int lt = 0; lt < 4; ++lt) {
        union { short8 s; uint4 u; } B0, B1;
        B0.u = *(const uint4*)&seq[w][(16 * lt + n) * 36 + 4 * q];
        B1.u = *(const uint4*)&seq[w][(16 * lt + n) * 36 + 16 + 4 * q];

        f32x4 rsum = {0.f, 0.f, 0.f, 0.f};
        rsum = __builtin_amdgcn_mfma_f32_16x16x32_bf16(ones8, B0.s, rsum, 0, 0, 0);
        rsum = __builtin_amdgcn_mfma_f32_16x16x32_bf16(ones8, B1.s, rsum, 0, 0, 0);
        float rsv = rsum[0];

        float xacc = 0.0f;
#pragma unroll
        for (int et = 0; et < 4; ++et) {
            f32x4 a = {0.f, 0.f, 0.f, 0.f};
            a = __builtin_amdgcn_mfma_f32_16x16x32_bf16(wa_f[et][0], B0.s, a, 0, 0, 0);
            a = __builtin_amdgcn_mfma_f32_16x16x32_bf16(wa_f[et][1], B1.s, a, 0, 0, 0);
#pragma unroll
            for (int r = 0; r < 4; ++r) {
                float t = fast_tanh(a[r] + biasv[et][r]);
                xacc = fmaf(t, idv[et][r], xacc);
            }
        }
        xacc += __shfl_xor(xacc, 16, 64);
        xacc += __shfl_xor(xacc, 32, 64);
        xs[lt] = (rsv == 0.0f) ? 0.0f : xacc;
    }

    float ex[4];
    float tot = 0.0f;
#pragma unroll
    for (int lt = 0; lt < 4; ++lt) {
        int l = 16 * lt + n;
        ex[lt] = (l < MAXLEN) ? __expf(xs[lt]) : 0.0f;
        tot += ex[lt];
    }
    tot += __shfl_xor(tot, 1, 64);
    tot += __shfl_xor(tot, 2, 64);
    tot += __shfl_xor(tot, 4, 64);
    tot += __shfl_xor(tot, 8, 64);
    float inv = 1.0f / (tot + 1e-12f);
    if (lane < 16) {
#pragma unroll
        for (int lt = 0; lt < 4; ++lt)
            attn_l[w][16 * lt + lane] = ex[lt] * inv;
    }

    float pooled = 0.0f;
    for (int l = 0; l < MAXLEN; ++l) {
        float a = attn_l[w][l];
        unsigned uu = seq[w][l * 36 + (lane >> 1)];
        float sv = (lane & 1) ? bf_hi(uu) : bf_lo(uu);
        pooled = fmaf(a, sv, pooled);
    }
    pooled_l[w][lane] = pooled;

    float o = 0.0f;
#pragma unroll 8
    for (int d = 0; d < 64; ++d) {
        float pv = pooled_l[w][d];
        float wv = bf_s(wgT[d * 72 + lane]);
        o = fmaf(pv, wv, o);
    }
    out[(size_t)b * 64 + lane] = 0.5f * idrow[w][lane] + 0.5f * o;
}

// ---------------- launch ----------------

extern "C" void kernel_launch(void* const* d_in, const int* in_sizes, int n_in,
                              void* d_out, int out_size, void* d_ws, size_t ws_size,
                              hipStream_t stream)
{
    const float* user_table = (const float*)d_in[0];
    const float* item_table = (const float*)d_in[1];
    const float* ev_uv      = (const float*)d_in[2];
    const float* ev_vu      = (const float*)d_in[3];
    const float* Watt       = (const float*)d_in[4];
    const float* Wb         = (const float*)d_in[5];
    const float* Wagg       = (const float*)d_in[6];
    const int*   edge_u     = (const int*)d_in[7];
    const int*   edge_i     = (const int*)d_in[8];
    const int*   uidx       = (const int*)d_in[9];
    const int*   ctx        = (const int*)d_in[10];
    float* out = (float*)d_out;

    const size_t NCAP = (size_t)NBU * CAP;  // 1201152 entries per direction

    // workspace layout (~56 MB)
    char* p = (char*)d_ws;
    unsigned* it_bf    = (unsigned*)p; p += (size_t)N_ITEMS * 32 * 4;   // 6.4 MB
    unsigned* u_msg_bf = (unsigned*)p; p += (size_t)N_USERS * 32 * 4;   // 12.8 MB
    unsigned* V1_bf    = (unsigned*)p; p += (size_t)N_ITEMS * 32 * 4;   // 6.4 MB
    // staged region (19.2 MB) — Vf_bf (6.4 MB) aliases it; staged dead by then
    char*     Sreg     = p;            p += NCAP * 8 * 2;               // 19.2 MB
    int2*     staged_u = (int2*)Sreg;
    int2*     staged_i = (int2*)(Sreg + NCAP * 8);
    unsigned* Vf_bf    = (unsigned*)Sreg;
    unsigned* csr_u    = (unsigned*)p; p += NCAP * 4;                   // 4.8 MB
    unsigned* csr_i    = (unsigned*)p; p += NCAP * 4;                   // 4.8 MB
    int2*     offend_u = (int2*)p;     p += (size_t)N_USERS * 8;        // 0.8 MB
    int2*     offend_i = (int2*)p;     p += (size_t)N_ITEMS * 8;        // 0.4 MB
    int*      gcur_u   = (int*)p;      p += NBU * 4;                    // contiguous
    int*      gcur_i   = (int*)p;      p += NBI * 4;                    //  pair

    // zero within-bucket cursors
    hipMemsetAsync(gcur_u, 0, (NBU + NBI) * 4, stream);

    convert_kernel<<<(N_ITEMS * 32 + 255) / 256, 256, 0, stream>>>(
        item_table, it_bf, N_ITEMS * 32);

    bin_kernel<<<2 * BBLOCKS, 512, 0, stream>>>(edge_u, edge_i, ev_uv, ev_vu,
                                                gcur_u, gcur_i, staged_u, staged_i);
    place_kernel<<<NBU + NBI, 256, 0, stream>>>(staged_u, staged_i, gcur_u, gcur_i,
                                                csr_u, csr_i, offend_u, offend_i);

    // 32 rows per block (4 waves x 8 eighth-wave rows)
    const int ublocks = (N_USERS + 31) / 32;
    const int iblocks = (N_ITEMS + 31) / 32;

    // layer 1
    gather_bf_kernel<16><<<ublocks, 256, 0, stream>>>(it_bf, csr_u, offend_u, u_msg_bf, N_USERS);
    gather_bf_kernel<17><<<iblocks, 256, 0, stream>>>(u_msg_bf, csr_i, offend_i, V1_bf, N_ITEMS);
    // layer 2 (+ fused combine -> Vf bf16; aliases dead staged region)
    gather_bf_kernel<16><<<ublocks, 256, 0, stream>>>(V1_bf, csr_u, offend_u, u_msg_bf, N_USERS);
    gather_final_bf_kernel<<<iblocks, 256, 0, stream>>>(u_msg_bf, csr_i, offend_i,
                                                        item_table, V1_bf, Vf_bf);

    // attention pooling + output (MFMA)
    phase2_kernel<<<BATCH / 4, 256, 0, stream>>>(user_table, Vf_bf, Watt, Wb, Wagg,
                                                 uidx, ctx, out);
}